// Round 17
// baseline (206.254 us; speedup 1.0000x reference)
//
#include <hip/hip_runtime.h>

// GraphSAGE (2 SAGEConv mean-agg layers + linear head) on MI355X.
// N=100000 nodes, E=1600000 edges, D=64 channels, OUT=32.
//
// Round-17 (vs verified r16):
//  * bin_prep: dst values kept in 16 regs from the histogram pass; staging
//    pass re-reads only src (-12.8MB traffic).
//  * fused_layer: persistent 2048-block grid with tile-stride loop
//    (+ loop-end barrier for LDS reuse); gather inner loop untouched.

#define D 64
#define OUTD 32
#define REG_SHIFT 8
#define REG_SIZE 256
#define BCHUNK 4096
#define PADQ 8                   // pad node lists to multiple of 8
#define CAP 5120                 // ebuf capacity per region
#define OUTCAP 8960              // colP capacity per region
#define FGRID 2048               // persistent fused grid (8 blocks/CU)

// ---------------- workspace layout (int units) ----------------
#define OFF_RCUR     64         // 512
#define OFF_DEG      576        // N padded-deg (reserve 100352)
#define OFF_ROWSTART 100928     // N
#define OFF_INV      201280     // N floats
#define OFF_COL      301632     // 391*OUTCAP = 3503360
#define OFF_EBUF     3804992    // 391*CAP = 2001920
#define OFF_XB       5806912    // (N+1)*32
#define OFF_H1B      9006944    // (N+1)*32
#define OFF_WC1      15406976   // 4096
#define OFF_WC2      15411072   // 4096
#define OFF_WHB      15415168   // 1024

typedef __attribute__((ext_vector_type(8))) short bf16x8;
typedef __attribute__((ext_vector_type(4))) float f32x4;
typedef __attribute__((ext_vector_type(2))) float f32x2;

__device__ __forceinline__ unsigned short bf16rne(float x) {
    unsigned u = __float_as_uint(x);
    unsigned r = (u + 0x7FFFu + ((u >> 16) & 1u)) >> 16;
    return (unsigned short)r;
}

// Fused: blocks < bblocks bin edges into region segments; the rest do prep
// (fp32->bf16 cast of x, zero rows, weight concat). Per-block int64 detect.
__global__ __launch_bounds__(256) void bin_prep(
        const int* __restrict__ e32,
        int* __restrict__ rcur, int* __restrict__ ebuf, int E, int NR, int bblocks,
        const float* __restrict__ x, unsigned short* __restrict__ xb,
        unsigned short* __restrict__ h1b,
        const float* __restrict__ w1l, const float* __restrict__ w1r,
        const float* __restrict__ w2l, const float* __restrict__ w2r,
        const float* __restrict__ wh,
        unsigned short* __restrict__ wcat1, unsigned short* __restrict__ wcat2,
        unsigned short* __restrict__ whb, int n4, int N) {
    __shared__ int stage[BCHUNK];
    __shared__ unsigned short rgn[BCHUNK];
    __shared__ int hist[512], lbase[512], startr[512], s1[512];
    int t = threadIdx.x;

    if (blockIdx.x >= bblocks) {
        // ---------------- prep path ----------------
        int i = (blockIdx.x - bblocks) * 256 + t;
        if (i < n4) {
            float4 v = ((const float4*)x)[i];
            unsigned lo = (unsigned)bf16rne(v.x) | ((unsigned)bf16rne(v.y) << 16);
            unsigned hi = (unsigned)bf16rne(v.z) | ((unsigned)bf16rne(v.w) << 16);
            ((uint2*)xb)[i] = make_uint2(lo, hi);
            return;
        }
        int j = i - n4;
        if (j < 16) {
            ((uint2*)xb)[(size_t)N * 16 + j] = make_uint2(0u, 0u);
        } else if (j < 32) {
            ((uint2*)h1b)[(size_t)N * 16 + (j - 16)] = make_uint2(0u, 0u);
        } else if (j < 32 + 8192) {
            int q = j - 32;
            int o = q >> 7, k = q & 127;
            wcat1[q] = bf16rne(k < 64 ? w1l[o * 64 + k] : w1r[o * 64 + k - 64]);
        } else if (j < 32 + 16384) {
            int q = j - 32 - 8192;
            int o = q >> 7, k = q & 127;
            wcat2[q] = bf16rne(k < 64 ? w2l[o * 64 + k] : w2r[o * 64 + k - 64]);
        } else if (j < 32 + 16384 + 2048) {
            int q = j - 32 - 16384;
            whb[q] = bf16rne(wh[q]);
        }
        return;
    }

    // ---------------- bin path ----------------
    int vflag = (t < 64) ? (e32[2 * t + 1] != 0) : 0;
    int mode = __syncthreads_or(vflag) ? 0 : 1;

    int base = blockIdx.x * BCHUNK;
    // Load this thread's 16 dst values ONCE; reuse in the staging pass.
    int dreg[16];
#pragma unroll
    for (int k = 0; k < 16; ++k) {
        int i = base + t + k * 256;
        dreg[k] = (i < E) ? (mode ? e32[2 * (E + i)] : e32[E + i]) : -1;
    }

    for (int i = t; i < 512; i += 256) hist[i] = 0;
    __syncthreads();
#pragma unroll
    for (int k = 0; k < 16; ++k)
        if (dreg[k] >= 0) atomicAdd(&hist[dreg[k] >> REG_SHIFT], 1);
    __syncthreads();
    {
        int* a = lbase; int* b = s1;
        for (int i = t; i < 512; i += 256) a[i] = hist[i];
        __syncthreads();
        for (int off = 1; off < 512; off <<= 1) {
            for (int i = t; i < 512; i += 256)
                b[i] = a[i] + ((i >= off) ? a[i - off] : 0);
            __syncthreads();
            int* tmp = a; a = b; b = tmp;
        }
        for (int i = t; i < 512; i += 256) {
            int incl = a[i];
            int ex = incl - hist[i];
            __syncthreads();
            lbase[i] = ex;
        }
        __syncthreads();
    }
    for (int i = t; i < 512; i += 256) {
        int st = 0;
        if (i < NR && hist[i] > 0) {
            st = i * CAP + atomicAdd(&rcur[i], hist[i]);   // rcur zero-based
            int lim = (i + 1) * CAP - hist[i];
            if (st > lim) st = lim;            // safety clamp (won't trigger)
        }
        startr[i] = st;
    }
    __syncthreads();
    for (int i = t; i < 512; i += 256) hist[i] = 0;
    __syncthreads();
#pragma unroll
    for (int k = 0; k < 16; ++k) {
        int i = base + t + k * 256;
        if (dreg[k] >= 0) {
            int s = mode ? e32[2 * i] : e32[i];
            int d = dreg[k];
            int r = d >> REG_SHIFT;
            int o = atomicAdd(&hist[r], 1);
            int pos = lbase[r] + o;
            stage[pos] = ((d & (REG_SIZE - 1)) << 24) | s;
            rgn[pos] = (unsigned short)r;
        }
    }
    __syncthreads();
    int count = E - base; if (count > BCHUNK) count = BCHUNK;
    for (int i = t; i < count; i += 256) {
        int r = rgn[i];
        ebuf[startr[r] + (i - lbase[r])] = stage[i];
    }
}

// Per-region local CSR build with zero-row padding (byte offsets, x8 pad).
__global__ __launch_bounds__(256) void build_csr(
        const int* __restrict__ ebuf, const int* __restrict__ rcur,
        int* __restrict__ degP, int* __restrict__ rowStartP, float* __restrict__ inv,
        int* __restrict__ colP, int N) {
    __shared__ int hist[REG_SIZE], cur[REG_SIZE], sA[REG_SIZE], sB[REG_SIZE];
    int r = blockIdx.x;
    int t = threadIdx.x;
    int lo = r << REG_SHIFT;
    int e0 = r * CAP, e1 = r * CAP + rcur[r];   // rcur zero-based count
    int colPbase = r * OUTCAP;
    hist[t] = 0;
    __syncthreads();
    for (int i = e0 + t; i < e1; i += 256)
        atomicAdd(&hist[((unsigned)ebuf[i]) >> 24], 1);
    __syncthreads();
    int v = hist[t];
    int vp = (v + PADQ - 1) & ~(PADQ - 1);
    int* a = sA; int* b = sB;
    a[t] = vp;
    __syncthreads();
    for (int off = 1; off < 256; off <<= 1) {
        b[t] = a[t] + ((t >= off) ? a[t - off] : 0);
        __syncthreads();
        int* tmp = a; a = b; b = tmp;
    }
    int startP = colPbase + (a[t] - vp);
    int node = lo + t;
    if (node < N) {
        degP[node] = vp;
        rowStartP[node] = startP;
        inv[node] = 1.0f / (float)(v > 0 ? v : 1);
    }
    cur[t] = startP;
    __syncthreads();
    for (int i = e0 + t; i < e1; i += 256) {
        int p = ebuf[i];
        int pos = atomicAdd(&cur[((unsigned)p) >> 24], 1);
        colP[pos] = (p & 0xFFFFFF) << 7;        // byte offset
    }
    __syncthreads();
    int zoff = N << 7;
    for (int k = startP + v; k < startP + vp; ++k) colP[k] = zoff;
}

// Fused SAGE layer: gather (phase 1, r16-verified loop) + MFMA dense
// (phase 2) (+ head). Persistent grid: each block loops over tiles.
template <bool HEAD>
__global__ __launch_bounds__(256, 8) void fused_layer(
        const unsigned short* __restrict__ hb,       // gather + own source
        const int* __restrict__ rowStartP, const int* __restrict__ degPv,
        const int* __restrict__ colP, const float* __restrict__ invdeg,
        const unsigned short* __restrict__ wcat,     // [64][128]
        const float* __restrict__ bias,              // [64]
        unsigned short* __restrict__ houtb,          // !HEAD out (bf16)
        const unsigned short* __restrict__ whb,      // [32][64]
        const float* __restrict__ bh,                // [32]
        float* __restrict__ outp,                    // [N][32]
        int n, int ntiles) {
    __shared__ unsigned meanT[16 * 32];              // swizzled (16B blocks)
    __shared__ unsigned short hT[HEAD ? 16 * 64 : 64];

    const int lane = threadIdx.x & 63;
    const int w    = threadIdx.x >> 6;
    const int half = lane >> 5, l31 = lane & 31;
    const int l15  = lane & 15, kg  = lane >> 4;
    const char* hbC = (const char*)hb;
    unsigned voff = (unsigned)(l31 << 2);

    for (int tile = blockIdx.x; tile < ntiles; tile += FGRID) {
    const int nb = tile * 16;

    // Hoist per-node scalars for all 4 nodes of this wave.
    int rsA[4], dgA[4];
    float ivA[4];
#pragma unroll
    for (int q = 0; q < 4; ++q) {
        int node = nb + w * 4 + q;
        int nodeC = node < n ? node : n - 1;
        nodeC = __builtin_amdgcn_readfirstlane(nodeC);
        rsA[q] = rowStartP[nodeC];
        dgA[q] = degPv[nodeC];
        ivA[q] = invdeg[nodeC];
    }

    // ---------------- phase 1: gather 4 nodes per wave ----------------
    int cvN = colP[rsA[0] + lane];
#pragma unroll
    for (int q = 0; q < 4; ++q) {
        int cv0 = cvN;
        if (q < 3) cvN = colP[rsA[q + 1] + lane];

        int rs = rsA[q], dgp = dgA[q];
        f32x2 a0 = {0.f, 0.f}, a1 = {0.f, 0.f}, a2 = {0.f, 0.f}, a3 = {0.f, 0.f};
        f32x2 a4 = {0.f, 0.f}, a5 = {0.f, 0.f}, a6 = {0.f, 0.f}, a7 = {0.f, 0.f};

        for (int base = 0; base < dgp; base += 64) {
            int cv = (base == 0) ? cv0 : colP[rs + base + lane];
            int m = dgp - base; if (m > 64) m = 64;
            int pairs = m >> 1;             // multiple of 4
            int pb = half;                  // shfl index: 2*p + half
            int p = 0;
            for (; p + 8 <= pairs; p += 8) {
#define G(j, A) { \
                int cb = __shfl(cv, pb + 2 * (j)); \
                unsigned u = *(const unsigned*)(hbC + ((unsigned)cb + voff)); \
                f32x2 ww = {__uint_as_float(u << 16), __uint_as_float(u & 0xFFFF0000u)}; \
                A += ww; }
                G(0, a0)  G(1, a1)  G(2, a2)  G(3, a3)
                G(4, a4)  G(5, a5)  G(6, a6)  G(7, a7)
                pb += 16;
            }
            if (pairs & 4) {
                G(0, a0)  G(1, a1)  G(2, a2)  G(3, a3)
            }
#undef G
        }
        f32x2 s = ((a0 + a1) + (a2 + a3)) + ((a4 + a5) + (a6 + a7));
        float s0 = s.x + __shfl_xor(s.x, 32);
        float s1 = s.y + __shfl_xor(s.y, 32);
        float iv = ivA[q];
        if (!half) {
            int local = w * 4 + q;
            unsigned mo = (unsigned)bf16rne(s0 * iv) | ((unsigned)bf16rne(s1 * iv) << 16);
            int cb = l31 >> 2;
            meanT[local * 32 + ((cb ^ (local & 7)) << 2) + (l31 & 3)] = mo;
        }
    }
    __syncthreads();

    // ---------------- phase 2: dense, wave w -> output quadrant nt=w ----------------
    const int nt = w;
    bf16x8 Am[2];
#pragma unroll
    for (int s = 0; s < 2; ++s) {
        int cb = s * 4 + kg;
        Am[s] = *(const bf16x8*)&meanT[l15 * 32 + ((cb ^ (l15 & 7)) << 2)];
    }
    int arow = nb + l15; if (arow >= n) arow = n - 1;
    const unsigned short* orow = hb + (size_t)arow * 64 + kg * 8;
    bf16x8 Ao0 = *(const bf16x8*)(orow);
    bf16x8 Ao1 = *(const bf16x8*)(orow + 32);
    const unsigned short* wrow = wcat + (nt * 16 + l15) * 128 + kg * 8;
    bf16x8 B0 = *(const bf16x8*)(wrow);
    bf16x8 B1 = *(const bf16x8*)(wrow + 32);
    bf16x8 B2 = *(const bf16x8*)(wrow + 64);
    bf16x8 B3 = *(const bf16x8*)(wrow + 96);

    float bc = bias[nt * 16 + l15];
    f32x4 a = {bc, bc, bc, bc};
    a = __builtin_amdgcn_mfma_f32_16x16x32_bf16(Am[0], B0, a, 0, 0, 0);
    a = __builtin_amdgcn_mfma_f32_16x16x32_bf16(Am[1], B1, a, 0, 0, 0);
    a = __builtin_amdgcn_mfma_f32_16x16x32_bf16(Ao0,  B2, a, 0, 0, 0);
    a = __builtin_amdgcn_mfma_f32_16x16x32_bf16(Ao1,  B3, a, 0, 0, 0);

    if constexpr (!HEAD) {
#pragma unroll
        for (int r = 0; r < 4; ++r) {
            int rw = nb + kg * 4 + r;
            float h = fmaxf(a[r], 0.0f);
            if (rw < n) houtb[(size_t)rw * 64 + nt * 16 + l15] = bf16rne(h);
        }
    } else {
        int bGlob = nt * 2 + (l15 >> 3);
        int n7 = l15 & 7;
#pragma unroll
        for (int r = 0; r < 4; ++r) {
            int m = kg * 4 + r;
            float h = fmaxf(a[r], 0.0f);
            hT[m * 64 + ((bGlob ^ (m & 7)) * 8) + n7] = bf16rne(h);
        }
        __syncthreads();
        if (w < 2) {
            bf16x8 hA[2];
#pragma unroll
            for (int s = 0; s < 2; ++s) {
                int kb = s * 4 + kg;
                hA[s] = *(const bf16x8*)(hT + l15 * 64 + ((kb ^ (l15 & 7)) * 8));
            }
            const unsigned short* hrow = whb + (w * 16 + l15) * 64 + kg * 8;
            bf16x8 H0 = *(const bf16x8*)(hrow);
            bf16x8 H1 = *(const bf16x8*)(hrow + 32);
            float bc2 = bh[w * 16 + l15];
            f32x4 a2 = {bc2, bc2, bc2, bc2};
            a2 = __builtin_amdgcn_mfma_f32_16x16x32_bf16(hA[0], H0, a2, 0, 0, 0);
            a2 = __builtin_amdgcn_mfma_f32_16x16x32_bf16(hA[1], H1, a2, 0, 0, 0);
#pragma unroll
            for (int r = 0; r < 4; ++r) {
                int rw = nb + kg * 4 + r;
                if (rw < n) outp[(size_t)rw * 32 + w * 16 + l15] = a2[r];
            }
        }
    }
    __syncthreads();   // LDS reuse across tile iterations
    }
}

extern "C" void kernel_launch(void* const* d_in, const int* in_sizes, int n_in,
                              void* d_out, int out_size, void* d_ws, size_t ws_size,
                              hipStream_t stream) {
    const float* x   = (const float*)d_in[0];
    const int* edges = (const int*)d_in[1];
    const float* w1l = (const float*)d_in[2];
    const float* b1  = (const float*)d_in[3];
    const float* w1r = (const float*)d_in[4];
    const float* w2l = (const float*)d_in[5];
    const float* b2  = (const float*)d_in[6];
    const float* w2r = (const float*)d_in[7];
    const float* wh  = (const float*)d_in[8];
    const float* bh  = (const float*)d_in[9];
    float* out = (float*)d_out;

    const int N = in_sizes[0] / D;   // 100000
    const int E = in_sizes[1] / 2;   // 1600000
    const int NR = (N + REG_SIZE - 1) >> REG_SHIFT;   // 391

    int* ws = (int*)d_ws;
    int*            rcur     = ws + OFF_RCUR;
    int*            degP     = ws + OFF_DEG;
    int*            rowStartP= ws + OFF_ROWSTART;
    float*          inv      = (float*)(ws + OFF_INV);
    int*            colP     = ws + OFF_COL;
    int*            ebuf     = ws + OFF_EBUF;
    unsigned short* xb       = (unsigned short*)(ws + OFF_XB);
    unsigned short* h1b      = (unsigned short*)(ws + OFF_H1B);
    unsigned short* wcat1    = (unsigned short*)(ws + OFF_WC1);
    unsigned short* wcat2    = (unsigned short*)(ws + OFF_WC2);
    unsigned short* whb      = (unsigned short*)(ws + OFF_WHB);

    // ---- CSR build + prep ----
    hipMemsetAsync(rcur, 0, 512 * sizeof(int), stream);
    int bblocks = (E + BCHUNK - 1) / BCHUNK;                  // 391
    int n4 = N * D / 4;
    int pblocks = (n4 + 32 + 16384 + 2048 + 255) / 256;       // ~6323
    bin_prep<<<bblocks + pblocks, 256, 0, stream>>>(
        edges, rcur, ebuf, E, NR, bblocks,
        x, xb, h1b, w1l, w1r, w2l, w2r, wh, wcat1, wcat2, whb, n4, N);
    build_csr<<<NR, 256, 0, stream>>>(ebuf, rcur, degP, rowStartP, inv, colP, N);

    int ntiles = (N + 15) / 16;   // 6250

    // ---- layer 1 (gather + dense fused, persistent grid) ----
    fused_layer<false><<<FGRID, 256, 0, stream>>>(
        xb, rowStartP, degP, colP, inv, wcat1, b1,
        h1b, nullptr, nullptr, nullptr, N, ntiles);
    // ---- layer 2 + head (fused, persistent grid) ----
    fused_layer<true><<<FGRID, 256, 0, stream>>>(
        h1b, rowStartP, degP, colP, inv, wcat2, b2,
        nullptr, whb, bh, out, N, ntiles);
}

// Round 18
// 132.275 us; speedup vs baseline: 1.5593x; 1.5593x over previous
//
#include <hip/hip_runtime.h>

// GraphSAGE (2 SAGEConv mean-agg layers + linear head) on MI355X.
// N=100000 nodes, E=1600000 edges, D=64 channels, OUT=32.
//
// Round-18: r17's persistent fused grid regressed (per-tile barrier +
// locality loss: 46->89us) -> fused_layer reverted to the exact r16 form
// (one 16-node tile per block, grid=6250). Kept r17's bin_prep register-dst
// optimization (-12.8MB re-read). Everything else verified r16.

#define D 64
#define OUTD 32
#define REG_SHIFT 8
#define REG_SIZE 256
#define BCHUNK 4096
#define PADQ 8                   // pad node lists to multiple of 8
#define CAP 5120                 // ebuf capacity per region
#define OUTCAP 8960              // colP capacity per region

// ---------------- workspace layout (int units) ----------------
#define OFF_RCUR     64         // 512
#define OFF_DEG      576        // N padded-deg (reserve 100352)
#define OFF_ROWSTART 100928     // N
#define OFF_INV      201280     // N floats
#define OFF_COL      301632     // 391*OUTCAP = 3503360
#define OFF_EBUF     3804992    // 391*CAP = 2001920
#define OFF_XB       5806912    // (N+1)*32
#define OFF_H1B      9006944    // (N+1)*32
#define OFF_WC1      15406976   // 4096
#define OFF_WC2      15411072   // 4096
#define OFF_WHB      15415168   // 1024

typedef __attribute__((ext_vector_type(8))) short bf16x8;
typedef __attribute__((ext_vector_type(4))) float f32x4;
typedef __attribute__((ext_vector_type(2))) float f32x2;

__device__ __forceinline__ unsigned short bf16rne(float x) {
    unsigned u = __float_as_uint(x);
    unsigned r = (u + 0x7FFFu + ((u >> 16) & 1u)) >> 16;
    return (unsigned short)r;
}

// Fused: blocks < bblocks bin edges into region segments; the rest do prep
// (fp32->bf16 cast of x, zero rows, weight concat). Per-block int64 detect.
__global__ __launch_bounds__(256) void bin_prep(
        const int* __restrict__ e32,
        int* __restrict__ rcur, int* __restrict__ ebuf, int E, int NR, int bblocks,
        const float* __restrict__ x, unsigned short* __restrict__ xb,
        unsigned short* __restrict__ h1b,
        const float* __restrict__ w1l, const float* __restrict__ w1r,
        const float* __restrict__ w2l, const float* __restrict__ w2r,
        const float* __restrict__ wh,
        unsigned short* __restrict__ wcat1, unsigned short* __restrict__ wcat2,
        unsigned short* __restrict__ whb, int n4, int N) {
    __shared__ int stage[BCHUNK];
    __shared__ unsigned short rgn[BCHUNK];
    __shared__ int hist[512], lbase[512], startr[512], s1[512];
    int t = threadIdx.x;

    if (blockIdx.x >= bblocks) {
        // ---------------- prep path ----------------
        int i = (blockIdx.x - bblocks) * 256 + t;
        if (i < n4) {
            float4 v = ((const float4*)x)[i];
            unsigned lo = (unsigned)bf16rne(v.x) | ((unsigned)bf16rne(v.y) << 16);
            unsigned hi = (unsigned)bf16rne(v.z) | ((unsigned)bf16rne(v.w) << 16);
            ((uint2*)xb)[i] = make_uint2(lo, hi);
            return;
        }
        int j = i - n4;
        if (j < 16) {
            ((uint2*)xb)[(size_t)N * 16 + j] = make_uint2(0u, 0u);
        } else if (j < 32) {
            ((uint2*)h1b)[(size_t)N * 16 + (j - 16)] = make_uint2(0u, 0u);
        } else if (j < 32 + 8192) {
            int q = j - 32;
            int o = q >> 7, k = q & 127;
            wcat1[q] = bf16rne(k < 64 ? w1l[o * 64 + k] : w1r[o * 64 + k - 64]);
        } else if (j < 32 + 16384) {
            int q = j - 32 - 8192;
            int o = q >> 7, k = q & 127;
            wcat2[q] = bf16rne(k < 64 ? w2l[o * 64 + k] : w2r[o * 64 + k - 64]);
        } else if (j < 32 + 16384 + 2048) {
            int q = j - 32 - 16384;
            whb[q] = bf16rne(wh[q]);
        }
        return;
    }

    // ---------------- bin path ----------------
    int vflag = (t < 64) ? (e32[2 * t + 1] != 0) : 0;
    int mode = __syncthreads_or(vflag) ? 0 : 1;

    int base = blockIdx.x * BCHUNK;
    // Load this thread's 16 dst values ONCE; reuse in the staging pass.
    int dreg[16];
#pragma unroll
    for (int k = 0; k < 16; ++k) {
        int i = base + t + k * 256;
        dreg[k] = (i < E) ? (mode ? e32[2 * (E + i)] : e32[E + i]) : -1;
    }

    for (int i = t; i < 512; i += 256) hist[i] = 0;
    __syncthreads();
#pragma unroll
    for (int k = 0; k < 16; ++k)
        if (dreg[k] >= 0) atomicAdd(&hist[dreg[k] >> REG_SHIFT], 1);
    __syncthreads();
    {
        int* a = lbase; int* b = s1;
        for (int i = t; i < 512; i += 256) a[i] = hist[i];
        __syncthreads();
        for (int off = 1; off < 512; off <<= 1) {
            for (int i = t; i < 512; i += 256)
                b[i] = a[i] + ((i >= off) ? a[i - off] : 0);
            __syncthreads();
            int* tmp = a; a = b; b = tmp;
        }
        for (int i = t; i < 512; i += 256) {
            int incl = a[i];
            int ex = incl - hist[i];
            __syncthreads();
            lbase[i] = ex;
        }
        __syncthreads();
    }
    for (int i = t; i < 512; i += 256) {
        int st = 0;
        if (i < NR && hist[i] > 0) {
            st = i * CAP + atomicAdd(&rcur[i], hist[i]);   // rcur zero-based
            int lim = (i + 1) * CAP - hist[i];
            if (st > lim) st = lim;            // safety clamp (won't trigger)
        }
        startr[i] = st;
    }
    __syncthreads();
    for (int i = t; i < 512; i += 256) hist[i] = 0;
    __syncthreads();
#pragma unroll
    for (int k = 0; k < 16; ++k) {
        int i = base + t + k * 256;
        if (dreg[k] >= 0) {
            int s = mode ? e32[2 * i] : e32[i];
            int d = dreg[k];
            int r = d >> REG_SHIFT;
            int o = atomicAdd(&hist[r], 1);
            int pos = lbase[r] + o;
            stage[pos] = ((d & (REG_SIZE - 1)) << 24) | s;
            rgn[pos] = (unsigned short)r;
        }
    }
    __syncthreads();
    int count = E - base; if (count > BCHUNK) count = BCHUNK;
    for (int i = t; i < count; i += 256) {
        int r = rgn[i];
        ebuf[startr[r] + (i - lbase[r])] = stage[i];
    }
}

// Per-region local CSR build with zero-row padding (byte offsets, x8 pad).
__global__ __launch_bounds__(256) void build_csr(
        const int* __restrict__ ebuf, const int* __restrict__ rcur,
        int* __restrict__ degP, int* __restrict__ rowStartP, float* __restrict__ inv,
        int* __restrict__ colP, int N) {
    __shared__ int hist[REG_SIZE], cur[REG_SIZE], sA[REG_SIZE], sB[REG_SIZE];
    int r = blockIdx.x;
    int t = threadIdx.x;
    int lo = r << REG_SHIFT;
    int e0 = r * CAP, e1 = r * CAP + rcur[r];   // rcur zero-based count
    int colPbase = r * OUTCAP;
    hist[t] = 0;
    __syncthreads();
    for (int i = e0 + t; i < e1; i += 256)
        atomicAdd(&hist[((unsigned)ebuf[i]) >> 24], 1);
    __syncthreads();
    int v = hist[t];
    int vp = (v + PADQ - 1) & ~(PADQ - 1);
    int* a = sA; int* b = sB;
    a[t] = vp;
    __syncthreads();
    for (int off = 1; off < 256; off <<= 1) {
        b[t] = a[t] + ((t >= off) ? a[t - off] : 0);
        __syncthreads();
        int* tmp = a; a = b; b = tmp;
    }
    int startP = colPbase + (a[t] - vp);
    int node = lo + t;
    if (node < N) {
        degP[node] = vp;
        rowStartP[node] = startP;
        inv[node] = 1.0f / (float)(v > 0 ? v : 1);
    }
    cur[t] = startP;
    __syncthreads();
    for (int i = e0 + t; i < e1; i += 256) {
        int p = ebuf[i];
        int pos = atomicAdd(&cur[((unsigned)p) >> 24], 1);
        colP[pos] = (p & 0xFFFFFF) << 7;        // byte offset
    }
    __syncthreads();
    int zoff = N << 7;
    for (int k = startP + v; k < startP + vp; ++k) colP[k] = zoff;
}

// Fused SAGE layer: gather (phase 1, r16-verified loop) + MFMA dense
// (phase 2) (+ head). One 16-node tile per block (4 waves).
template <bool HEAD>
__global__ __launch_bounds__(256, 8) void fused_layer(
        const unsigned short* __restrict__ hb,       // gather + own source
        const int* __restrict__ rowStartP, const int* __restrict__ degPv,
        const int* __restrict__ colP, const float* __restrict__ invdeg,
        const unsigned short* __restrict__ wcat,     // [64][128]
        const float* __restrict__ bias,              // [64]
        unsigned short* __restrict__ houtb,          // !HEAD out (bf16)
        const unsigned short* __restrict__ whb,      // [32][64]
        const float* __restrict__ bh,                // [32]
        float* __restrict__ outp,                    // [N][32]
        int n) {
    __shared__ unsigned meanT[16 * 32];              // swizzled (16B blocks)
    __shared__ unsigned short hT[HEAD ? 16 * 64 : 64];

    const int lane = threadIdx.x & 63;
    const int w    = threadIdx.x >> 6;
    const int half = lane >> 5, l31 = lane & 31;
    const int l15  = lane & 15, kg  = lane >> 4;
    const char* hbC = (const char*)hb;
    unsigned voff = (unsigned)(l31 << 2);

    const int nb = blockIdx.x * 16;

    // Hoist per-node scalars for all 4 nodes of this wave.
    int rsA[4], dgA[4];
    float ivA[4];
#pragma unroll
    for (int q = 0; q < 4; ++q) {
        int node = nb + w * 4 + q;
        int nodeC = node < n ? node : n - 1;
        nodeC = __builtin_amdgcn_readfirstlane(nodeC);
        rsA[q] = rowStartP[nodeC];
        dgA[q] = degPv[nodeC];
        ivA[q] = invdeg[nodeC];
    }

    // ---------------- phase 1: gather 4 nodes per wave ----------------
    int cvN = colP[rsA[0] + lane];
#pragma unroll
    for (int q = 0; q < 4; ++q) {
        int cv0 = cvN;
        if (q < 3) cvN = colP[rsA[q + 1] + lane];

        int rs = rsA[q], dgp = dgA[q];
        f32x2 a0 = {0.f, 0.f}, a1 = {0.f, 0.f}, a2 = {0.f, 0.f}, a3 = {0.f, 0.f};
        f32x2 a4 = {0.f, 0.f}, a5 = {0.f, 0.f}, a6 = {0.f, 0.f}, a7 = {0.f, 0.f};

        for (int base = 0; base < dgp; base += 64) {
            int cv = (base == 0) ? cv0 : colP[rs + base + lane];
            int m = dgp - base; if (m > 64) m = 64;
            int pairs = m >> 1;             // multiple of 4
            int pb = half;                  // shfl index: 2*p + half
            int p = 0;
            for (; p + 8 <= pairs; p += 8) {
#define G(j, A) { \
                int cb = __shfl(cv, pb + 2 * (j)); \
                unsigned u = *(const unsigned*)(hbC + ((unsigned)cb + voff)); \
                f32x2 ww = {__uint_as_float(u << 16), __uint_as_float(u & 0xFFFF0000u)}; \
                A += ww; }
                G(0, a0)  G(1, a1)  G(2, a2)  G(3, a3)
                G(4, a4)  G(5, a5)  G(6, a6)  G(7, a7)
                pb += 16;
            }
            if (pairs & 4) {
                G(0, a0)  G(1, a1)  G(2, a2)  G(3, a3)
            }
#undef G
        }
        f32x2 s = ((a0 + a1) + (a2 + a3)) + ((a4 + a5) + (a6 + a7));
        float s0 = s.x + __shfl_xor(s.x, 32);
        float s1 = s.y + __shfl_xor(s.y, 32);
        float iv = ivA[q];
        if (!half) {
            int local = w * 4 + q;
            unsigned mo = (unsigned)bf16rne(s0 * iv) | ((unsigned)bf16rne(s1 * iv) << 16);
            int cb = l31 >> 2;
            meanT[local * 32 + ((cb ^ (local & 7)) << 2) + (l31 & 3)] = mo;
        }
    }
    __syncthreads();

    // ---------------- phase 2: dense, wave w -> output quadrant nt=w ----------------
    const int nt = w;
    bf16x8 Am[2];
#pragma unroll
    for (int s = 0; s < 2; ++s) {
        int cb = s * 4 + kg;
        Am[s] = *(const bf16x8*)&meanT[l15 * 32 + ((cb ^ (l15 & 7)) << 2)];
    }
    int arow = nb + l15; if (arow >= n) arow = n - 1;
    const unsigned short* orow = hb + (size_t)arow * 64 + kg * 8;
    bf16x8 Ao0 = *(const bf16x8*)(orow);
    bf16x8 Ao1 = *(const bf16x8*)(orow + 32);
    const unsigned short* wrow = wcat + (nt * 16 + l15) * 128 + kg * 8;
    bf16x8 B0 = *(const bf16x8*)(wrow);
    bf16x8 B1 = *(const bf16x8*)(wrow + 32);
    bf16x8 B2 = *(const bf16x8*)(wrow + 64);
    bf16x8 B3 = *(const bf16x8*)(wrow + 96);

    float bc = bias[nt * 16 + l15];
    f32x4 a = {bc, bc, bc, bc};
    a = __builtin_amdgcn_mfma_f32_16x16x32_bf16(Am[0], B0, a, 0, 0, 0);
    a = __builtin_amdgcn_mfma_f32_16x16x32_bf16(Am[1], B1, a, 0, 0, 0);
    a = __builtin_amdgcn_mfma_f32_16x16x32_bf16(Ao0,  B2, a, 0, 0, 0);
    a = __builtin_amdgcn_mfma_f32_16x16x32_bf16(Ao1,  B3, a, 0, 0, 0);

    if constexpr (!HEAD) {
#pragma unroll
        for (int r = 0; r < 4; ++r) {
            int rw = nb + kg * 4 + r;
            float h = fmaxf(a[r], 0.0f);
            if (rw < n) houtb[(size_t)rw * 64 + nt * 16 + l15] = bf16rne(h);
        }
    } else {
        int bGlob = nt * 2 + (l15 >> 3);
        int n7 = l15 & 7;
#pragma unroll
        for (int r = 0; r < 4; ++r) {
            int m = kg * 4 + r;
            float h = fmaxf(a[r], 0.0f);
            hT[m * 64 + ((bGlob ^ (m & 7)) * 8) + n7] = bf16rne(h);
        }
        __syncthreads();
        if (w < 2) {
            bf16x8 hA[2];
#pragma unroll
            for (int s = 0; s < 2; ++s) {
                int kb = s * 4 + kg;
                hA[s] = *(const bf16x8*)(hT + l15 * 64 + ((kb ^ (l15 & 7)) * 8));
            }
            const unsigned short* hrow = whb + (w * 16 + l15) * 64 + kg * 8;
            bf16x8 H0 = *(const bf16x8*)(hrow);
            bf16x8 H1 = *(const bf16x8*)(hrow + 32);
            float bc2 = bh[w * 16 + l15];
            f32x4 a2 = {bc2, bc2, bc2, bc2};
            a2 = __builtin_amdgcn_mfma_f32_16x16x32_bf16(hA[0], H0, a2, 0, 0, 0);
            a2 = __builtin_amdgcn_mfma_f32_16x16x32_bf16(hA[1], H1, a2, 0, 0, 0);
#pragma unroll
            for (int r = 0; r < 4; ++r) {
                int rw = nb + kg * 4 + r;
                if (rw < n) outp[(size_t)rw * 32 + w * 16 + l15] = a2[r];
            }
        }
    }
}

extern "C" void kernel_launch(void* const* d_in, const int* in_sizes, int n_in,
                              void* d_out, int out_size, void* d_ws, size_t ws_size,
                              hipStream_t stream) {
    const float* x   = (const float*)d_in[0];
    const int* edges = (const int*)d_in[1];
    const float* w1l = (const float*)d_in[2];
    const float* b1  = (const float*)d_in[3];
    const float* w1r = (const float*)d_in[4];
    const float* w2l = (const float*)d_in[5];
    const float* b2  = (const float*)d_in[6];
    const float* w2r = (const float*)d_in[7];
    const float* wh  = (const float*)d_in[8];
    const float* bh  = (const float*)d_in[9];
    float* out = (float*)d_out;

    const int N = in_sizes[0] / D;   // 100000
    const int E = in_sizes[1] / 2;   // 1600000
    const int NR = (N + REG_SIZE - 1) >> REG_SHIFT;   // 391

    int* ws = (int*)d_ws;
    int*            rcur     = ws + OFF_RCUR;
    int*            degP     = ws + OFF_DEG;
    int*            rowStartP= ws + OFF_ROWSTART;
    float*          inv      = (float*)(ws + OFF_INV);
    int*            colP     = ws + OFF_COL;
    int*            ebuf     = ws + OFF_EBUF;
    unsigned short* xb       = (unsigned short*)(ws + OFF_XB);
    unsigned short* h1b      = (unsigned short*)(ws + OFF_H1B);
    unsigned short* wcat1    = (unsigned short*)(ws + OFF_WC1);
    unsigned short* wcat2    = (unsigned short*)(ws + OFF_WC2);
    unsigned short* whb      = (unsigned short*)(ws + OFF_WHB);

    // ---- CSR build + prep ----
    hipMemsetAsync(rcur, 0, 512 * sizeof(int), stream);
    int bblocks = (E + BCHUNK - 1) / BCHUNK;                  // 391
    int n4 = N * D / 4;
    int pblocks = (n4 + 32 + 16384 + 2048 + 255) / 256;       // ~6323
    bin_prep<<<bblocks + pblocks, 256, 0, stream>>>(
        edges, rcur, ebuf, E, NR, bblocks,
        x, xb, h1b, w1l, w1r, w2l, w2r, wh, wcat1, wcat2, whb, n4, N);
    build_csr<<<NR, 256, 0, stream>>>(ebuf, rcur, degP, rowStartP, inv, colP, N);

    int ntiles = (N + 15) / 16;   // 6250

    // ---- layer 1 (gather + dense fused) ----
    fused_layer<false><<<ntiles, 256, 0, stream>>>(
        xb, rowStartP, degP, colP, inv, wcat1, b1,
        h1b, nullptr, nullptr, nullptr, N);
    // ---- layer 2 + head (fused) ----
    fused_layer<true><<<ntiles, 256, 0, stream>>>(
        h1b, rowStartP, degP, colP, inv, wcat2, b2,
        nullptr, whb, bh, out, N);
}